// Round 4
// baseline (173.649 us; speedup 1.0000x reference)
//
#include <hip/hip_runtime.h>
#include <hip/hip_bf16.h>
#include <math.h>

// Problem constants: B=32, U=4096, K=4, N=2, K2=2, STRIDE=2048, UN=2048
// ws: (2, 4, 2048, 8192) f32 = 512 MB  -> the traffic floor
// GEMM per j: (32 x 8192) @ (8192 x 8192), f32 vector-FMA (no fp32 MFMA on CDNA4)
//
// d_out layout (flat, return order):
//   x_out  [0,      131072)   (32,4096)
//   new_hs [131072, 393216)   (2,2,32,2048)
//   new_c  [393216, 917504)   (2,4,32,2048)
//
// d_ws layout:
//   in_t    at byte 0    : 2*8192*32 f32 = 2 MB       (in_t[j][k][b])
//   partial at byte 2 MB : 2*16*32*8192 f32 = 33.5 MB (partial[j][s][b][f])

#define IN_T_ELEMS (2 * 8192 * 32)
#define NSPLIT 16

__global__ __launch_bounds__(256) void transpose_in(const float* __restrict__ x,
                                                    const float* __restrict__ hs,
                                                    float* __restrict__ in_t) {
    int tid = blockIdx.x * 256 + threadIdx.x;   // [0, 524288)
    int b   = tid & 31;
    int kkd = (tid >> 5) & 8191;
    int j   = tid >> 18;
    float v;
    if (kkd < 4096) {
        v = x[b * 4096 + kkd];                       // x_chunks[b][kk][d] = x[b][kkd]
    } else {
        int kk = kkd >> 11;                          // 2 or 3
        int d  = kkd & 2047;
        v = hs[((j * 2 + (kk - 2)) * 32 + b) * 2048 + d];   // hs (2,2,32,2048)
    }
    in_t[tid] = v;
}

__device__ __forceinline__ void fma_row(float acc[8][4], float4 a0, float4 a1, float4 wv) {
    acc[0][0] = fmaf(a0.x, wv.x, acc[0][0]);
    acc[0][1] = fmaf(a0.x, wv.y, acc[0][1]);
    acc[0][2] = fmaf(a0.x, wv.z, acc[0][2]);
    acc[0][3] = fmaf(a0.x, wv.w, acc[0][3]);
    acc[1][0] = fmaf(a0.y, wv.x, acc[1][0]);
    acc[1][1] = fmaf(a0.y, wv.y, acc[1][1]);
    acc[1][2] = fmaf(a0.y, wv.z, acc[1][2]);
    acc[1][3] = fmaf(a0.y, wv.w, acc[1][3]);
    acc[2][0] = fmaf(a0.z, wv.x, acc[2][0]);
    acc[2][1] = fmaf(a0.z, wv.y, acc[2][1]);
    acc[2][2] = fmaf(a0.z, wv.z, acc[2][2]);
    acc[2][3] = fmaf(a0.z, wv.w, acc[2][3]);
    acc[3][0] = fmaf(a0.w, wv.x, acc[3][0]);
    acc[3][1] = fmaf(a0.w, wv.y, acc[3][1]);
    acc[3][2] = fmaf(a0.w, wv.z, acc[3][2]);
    acc[3][3] = fmaf(a0.w, wv.w, acc[3][3]);
    acc[4][0] = fmaf(a1.x, wv.x, acc[4][0]);
    acc[4][1] = fmaf(a1.x, wv.y, acc[4][1]);
    acc[4][2] = fmaf(a1.x, wv.z, acc[4][2]);
    acc[4][3] = fmaf(a1.x, wv.w, acc[4][3]);
    acc[5][0] = fmaf(a1.y, wv.x, acc[5][0]);
    acc[5][1] = fmaf(a1.y, wv.y, acc[5][1]);
    acc[5][2] = fmaf(a1.y, wv.z, acc[5][2]);
    acc[5][3] = fmaf(a1.y, wv.w, acc[5][3]);
    acc[6][0] = fmaf(a1.z, wv.x, acc[6][0]);
    acc[6][1] = fmaf(a1.z, wv.y, acc[6][1]);
    acc[6][2] = fmaf(a1.z, wv.z, acc[6][2]);
    acc[6][3] = fmaf(a1.z, wv.w, acc[6][3]);
    acc[7][0] = fmaf(a1.w, wv.x, acc[7][0]);
    acc[7][1] = fmaf(a1.w, wv.y, acc[7][1]);
    acc[7][2] = fmaf(a1.w, wv.z, acc[7][2]);
    acc[7][3] = fmaf(a1.w, wv.w, acc[7][3]);
}

// Grid: 1024 blocks = 2 (j) x 32 (f-tile of 256) x 16 (K-chunk s). Block = 256 (4 waves),
// 4 blocks/CU. Wave w owns batches [w*8, w*8+8); lane owns 4 consecutive f.
// in_t staged through double-buffered LDS (sub-chunks of 128 K-rows x 32 batches = 16 KB),
// reg-staged with issue-early/write-late so HBM/L2 latency hides under the FMA phase.
// av reads are wave-uniform ds_read_b128 (broadcast, conflict-free).
// ws loads are 4-row register ping-pong (wa/wb), one block ahead.
__global__ __launch_bounds__(256, 4) void gemm_partial(const float* __restrict__ in_t,
                                                       const float* __restrict__ wsm,
                                                       float* __restrict__ partial) {
    __shared__ float lds[2][128][32];    // 32 KB

    int lin = blockIdx.x;
    int s   = lin & (NSPLIT - 1);
    int ft  = (lin >> 4) & 31;
    int j   = lin >> 9;
    int w    = __builtin_amdgcn_readfirstlane((int)(threadIdx.x >> 6));
    int lane = threadIdx.x & 63;
    int tid  = threadIdx.x;
    int f0   = ft * 256 + lane * 4;
    int k0   = s * 512;

    const float* __restrict__ itb  = in_t + (size_t)(j * 8192 + k0) * 32;       // sub-chunk src base
    const float* __restrict__ wrow = wsm + ((size_t)j * 8192 + k0) * 8192 + f0; // row-0 ws base

    float acc[8][4];
#pragma unroll
    for (int b = 0; b < 8; ++b)
#pragma unroll
        for (int q = 0; q < 4; ++q) acc[b][q] = 0.f;

    float4 stg[4];
    // stage sub-chunk 0 (16 KB: 4 x float4 per thread, coalesced)
#pragma unroll
    for (int i = 0; i < 4; ++i)
        stg[i] = *(const float4*)(itb + i * 1024 + tid * 4);
    // ws prologue: rows 0..3
    float4 wa[4], wb[4];
#pragma unroll
    for (int u = 0; u < 4; ++u)
        wa[u] = *(const float4*)(wrow + (size_t)u * 8192);
    // write stage -> buf0 (waits only on stg loads)
#pragma unroll
    for (int i = 0; i < 4; ++i)
        *(float4*)(&lds[0][0][0] + i * 1024 + tid * 4) = stg[i];
    __syncthreads();

    for (int c = 0; c < 4; ++c) {
        // issue next sub-chunk's staging loads early (complete during the 16 compute blocks)
        if (c < 3) {
            const float* src = itb + (c + 1) * 4096 + tid * 4;
#pragma unroll
            for (int i = 0; i < 4; ++i)
                stg[i] = *(const float4*)(src + i * 1024);
        }
        const float* cur = &lds[c & 1][0][0] + w * 8;   // wave-uniform LDS base
#pragma unroll 1
        for (int g = 0; g < 16; ++g) {
            int r = c * 128 + g * 8;
            // body A: prefetch ws rows r+4..r+7 -> wb; compute rows r..r+3 from wa
            {
                const float* p = wrow + (size_t)(r + 4) * 8192;
#pragma unroll
                for (int u = 0; u < 4; ++u)
                    wb[u] = *(const float4*)(p + (size_t)u * 8192);
            }
#pragma unroll
            for (int u = 0; u < 4; ++u) {
                const float* ar = cur + (g * 8 + u) * 32;
                float4 a0 = *(const float4*)ar;
                float4 a1 = *(const float4*)(ar + 4);
                fma_row(acc, a0, a1, wa[u]);
            }
            // body B: prefetch ws rows r+8..r+11 (clamped) -> wa; compute rows r+4..r+7 from wb
            {
                int nr = r + 8;
                if (nr >= 512) nr = 0;        // harmless re-read, keeps code branch-uniform
                const float* p = wrow + (size_t)nr * 8192;
#pragma unroll
                for (int u = 0; u < 4; ++u)
                    wa[u] = *(const float4*)(p + (size_t)u * 8192);
            }
#pragma unroll
            for (int u = 0; u < 4; ++u) {
                const float* ar = cur + (g * 8 + 4 + u) * 32;
                float4 a0 = *(const float4*)ar;
                float4 a1 = *(const float4*)(ar + 4);
                fma_row(acc, a0, a1, wb[u]);
            }
        }
        // write-late: stg regs -> other buffer (loads have had the whole compute phase)
        if (c < 3) {
            float* dst = &lds[(c + 1) & 1][0][0] + tid * 4;
#pragma unroll
            for (int i = 0; i < 4; ++i)
                *(float4*)(dst + i * 1024) = stg[i];
        }
        __syncthreads();
    }

    // partial[j][s][b][f]: coalesced float4 stores
    size_t pbase = ((size_t)((j * NSPLIT + s) * 32 + w * 8)) * 8192 + f0;
#pragma unroll
    for (int b = 0; b < 8; ++b)
        *(float4*)(partial + pbase + (size_t)b * 8192) = *(const float4*)acc[b];
}

__device__ __forceinline__ float sigmoidf_(float v) { return 1.f / (1.f + expf(-v)); }

// 131072 threads: tid -> (j, b, un)
__global__ __launch_bounds__(256) void epilogue(const float* __restrict__ partial,
                                                const float* __restrict__ cs,
                                                float* __restrict__ out) {
    int tid = blockIdx.x * 256 + threadIdx.x;
    int un  = tid & 2047;
    int b   = (tid >> 11) & 31;
    int j   = tid >> 16;

    float g4[4];
#pragma unroll
    for (int gate = 0; gate < 4; ++gate) {
        int f = gate * 2048 + un;
        float sum = 0.f;
#pragma unroll
        for (int s = 0; s < NSPLIT; ++s)
            sum += partial[((size_t)((j * NSPLIT + s) * 32 + b)) * 8192 + f];
        g4[gate] = sum;
    }
    float iv = sigmoidf_(g4[0]);
    float fv = sigmoidf_(g4[1]);
    float gv = tanhf(g4[2]);
    float ov = sigmoidf_(g4[3]);
    float ig = iv * gv;

#pragma unroll
    for (int kk = 0; kk < 4; ++kk) {
        float c_old = cs[((j * 4 + kk) * 32 + b) * 2048 + un];
        float c_new = fv * c_old + ig;
        float h     = ov * tanhf(c_new);
        out[393216 + ((j * 4 + kk) * 32 + b) * 2048 + un] = c_new;   // new_c
        if (kk == 0) {
            out[b * 4096 + j * 2048 + un] = h;                       // x_out
        }
        if (kk == j + 2) {
            // new_hs[jj][j][b][un] = h for jj in {0,1}
            out[131072 + ((0 * 2 + j) * 32 + b) * 2048 + un] = h;
            out[131072 + ((1 * 2 + j) * 32 + b) * 2048 + un] = h;
        }
    }
}

extern "C" void kernel_launch(void* const* d_in, const int* in_sizes, int n_in,
                              void* d_out, int out_size, void* d_ws, size_t ws_size,
                              hipStream_t stream) {
    const float* x   = (const float*)d_in[0];
    const float* hs  = (const float*)d_in[1];
    const float* cs  = (const float*)d_in[2];
    const float* wsm = (const float*)d_in[3];
    float* out = (float*)d_out;

    float* in_t    = (float*)d_ws;                                    // 2 MB
    float* partial = (float*)((char*)d_ws + (size_t)IN_T_ELEMS * 4);  // 33.5 MB

    transpose_in<<<524288 / 256, 256, 0, stream>>>(x, hs, in_t);
    gemm_partial<<<1024, 256, 0, stream>>>(in_t, wsm, partial);
    epilogue<<<131072 / 256, 256, 0, stream>>>(partial, cs, out);
}